// Round 1
// baseline (922.802 us; speedup 1.0000x reference)
//
#include <hip/hip_runtime.h>

#define EPSB 1e-5f
#define NEG 0.2f

__device__ __forceinline__ float lrelu(float y) { return y >= 0.f ? y : NEG * y; }

// ---------------------------------------------------------------------------
// Fused conv frontend: conv1(s5,p2)+BN+LReLU -> conv2(s4)+BN+LReLU ->
// conv3(s2)+BN+LReLU -> concat -> 1x1 conv +BN+LReLU -> transpose.
// One block per (batch b, j-slice q of 8); halos kept in LDS.
// Output xt[p][b][s]  (p<1287, b<32, s<32), i.e. xt[p*1024 + b*32 + s].
// ---------------------------------------------------------------------------
__global__ __launch_bounds__(256) void k_front(
    const float* __restrict__ data, const float* __restrict__ w1,
    const float* __restrict__ w2, const float* __restrict__ w3,
    const float* __restrict__ lw, const float* __restrict__ bg,
    const float* __restrict__ bb, const float* __restrict__ bm,
    const float* __restrict__ bv, float* __restrict__ xt)
{
  __shared__ float x1s[32][132];
  __shared__ float x2s[32][40];
  __shared__ float x3s[32][20];
  const int b = blockIdx.x >> 3, q = blockIdx.x & 7, t = threadIdx.x;
  const int o1s = (937*q)/8, o1e = (937*(q+1))/8;
  const int o2s = (234*q)/8, o2e = (234*(q+1))/8;
  const int o3s = (116*q)/8, o3e = (116*(q+1))/8;
  int n2s = min(o2s, 2*o3s);
  int n2e = max(o2e, 2*(o3e-1)+4); if (n2e > 234) n2e = 234;
  int n1s = min(o1s, 4*n2s);
  int n1e = max(o1e, 4*(n2e-1)+5); if (n1e > 937) n1e = 937;
  const int w1w = n1e - n1s, w2w = n2e - n2s, w3w = o3e - o3s;

  // stage 1: conv1 (Cin=1, K=5, stride 5, pad 2) + BN row0 + LReLU
  for (int idx = t; idx < 32*w1w; idx += 256) {
    int c = idx / w1w, j = n1s + idx % w1w;
    float acc = 0.f;
    int base = 5*j - 2;
    #pragma unroll
    for (int k = 0; k < 5; ++k) {
      int pos = base + k;
      float d = (pos >= 0 && pos < 4681) ? data[b*4681 + pos] : 0.f;
      acc += w1[c*5 + k] * d;
    }
    float sc = bg[c] * rsqrtf(bv[c] + EPSB);
    x1s[c][j - n1s] = lrelu((acc - bm[c]) * sc + bb[c]);
  }
  __syncthreads();
  // stage 2: conv2 (K=5, stride 4) + BN row1 + LReLU (compute halo range too)
  for (int idx = t; idx < 32*w2w; idx += 256) {
    int c = idx / w2w, j = n2s + idx % w2w;
    float acc = 0.f;
    int col = 4*j - n1s;
    for (int ci = 0; ci < 32; ++ci) {
      #pragma unroll
      for (int k = 0; k < 5; ++k) acc += w2[(c*32 + ci)*5 + k] * x1s[ci][col + k];
    }
    float sc = bg[32+c] * rsqrtf(bv[32+c] + EPSB);
    x2s[c][j - n2s] = lrelu((acc - bm[32+c]) * sc + bb[32+c]);
  }
  __syncthreads();
  // stage 3: conv3 (K=4, stride 2) + BN row2 + LReLU
  for (int idx = t; idx < 32*w3w; idx += 256) {
    int c = idx / w3w, j = o3s + idx % w3w;
    float acc = 0.f;
    int col = 2*j - n2s;
    for (int ci = 0; ci < 32; ++ci) {
      #pragma unroll
      for (int k = 0; k < 4; ++k) acc += w3[(c*32 + ci)*4 + k] * x2s[ci][col + k];
    }
    float sc = bg[64+c] * rsqrtf(bv[64+c] + EPSB);
    x3s[c][j - o3s] = lrelu((acc - bm[64+c]) * sc + bb[64+c]);
  }
  __syncthreads();
  // stage 4: 1x1 conv over concat + BN row3 + LReLU, write transposed xt[p][b][s]
  const int np1 = o1e - o1s, np2 = o2e - o2s, np3 = o3e - o3s;
  const int np = np1 + np2 + np3;
  for (int idx = t; idx < np*32; idx += 256) {
    int pi = idx >> 5, s = idx & 31;
    float acc = 0.f;
    int p;
    if (pi < np1) {
      int j = o1s + pi; p = j;
      int col = j - n1s;
      for (int ci = 0; ci < 32; ++ci) acc += lw[s*32 + ci] * x1s[ci][col];
    } else if (pi < np1 + np2) {
      int j = o2s + (pi - np1); p = 937 + j;
      int col = j - n2s;
      for (int ci = 0; ci < 32; ++ci) acc += lw[s*32 + ci] * x2s[ci][col];
    } else {
      int j = o3s + (pi - np1 - np2); p = 1171 + j;
      int col = j - o3s;
      for (int ci = 0; ci < 32; ++ci) acc += lw[s*32 + ci] * x3s[ci][col];
    }
    float sc = bg[96+s] * rsqrtf(bv[96+s] + EPSB);
    xt[p*1024 + b*32 + s] = lrelu((acc - bm[96+s]) * sc + bb[96+s]);
  }
}

// ---------------------------------------------------------------------------
// Pass A: u[bh][p][l][v][b16] = sum_s W[l,p,v,s] * x[b,p,s]; also atomic
// accumulate s0[l][v][b] = sum_p u (iter-0 coupling uses uniform c=1/40).
// One wave per (l, 16-p chunk); lane = vg*8+bg; thread tile = 5v x 4b.
// W read direct from global (8 lanes share each address -> coalesced).
// ---------------------------------------------------------------------------
__global__ __launch_bounds__(256) void k_uhat(
    const float* __restrict__ W, const float* __restrict__ xt,
    float* __restrict__ u, float* __restrict__ s0)
{
  const int wi = blockIdx.x*4 + (threadIdx.x >> 6);
  const int lane = threadIdx.x & 63;
  const int l = wi % 40, chunk = wi / 40;
  const int vg = lane >> 3, bg = lane & 7;
  const int bh = bg >> 2;             // b-half
  const int b16 = (bg & 3) * 4;       // b offset within half
  const int p0 = chunk * 16;
  float s0acc[5][4] = {};
  for (int pp = 0; pp < 16; ++pp) {
    int p = p0 + pp;
    if (p >= 1287) break;
    const float* Wt = W + (size_t)(l*1287 + p) * 1280;  // [v][s]
    const float* xp = xt + p*1024;                      // [b][s]
    float acc[5][4] = {};
    #pragma unroll 2
    for (int s4 = 0; s4 < 8; ++s4) {
      float4 wv[5], xv[4];
      #pragma unroll
      for (int i = 0; i < 5; ++i) wv[i] = *(const float4*)(Wt + (vg*5 + i)*32 + s4*4);
      #pragma unroll
      for (int j = 0; j < 4; ++j) xv[j] = *(const float4*)(xp + (bg*4 + j)*32 + s4*4);
      #pragma unroll
      for (int i = 0; i < 5; ++i)
        #pragma unroll
        for (int j = 0; j < 4; ++j)
          acc[i][j] += wv[i].x*xv[j].x + wv[i].y*xv[j].y + wv[i].z*xv[j].z + wv[i].w*xv[j].w;
    }
    float* up = u + ((size_t)(bh*1287 + p)*40 + l) * 640;  // [v][b16]
    #pragma unroll
    for (int i = 0; i < 5; ++i) {
      int v = vg*5 + i;
      *(float4*)(up + v*16 + b16) = make_float4(acc[i][0], acc[i][1], acc[i][2], acc[i][3]);
      #pragma unroll
      for (int j = 0; j < 4; ++j) s0acc[i][j] += acc[i][j];
    }
  }
  #pragma unroll
  for (int i = 0; i < 5; ++i) {
    int v = vg*5 + i;
    #pragma unroll
    for (int j = 0; j < 4; ++j)
      atomicAdd(&s0[(l*40 + v)*32 + bg*4 + j], s0acc[i][j]);
  }
}

// ---------------------------------------------------------------------------
// squash helpers: block per (b,l), 64 threads, thread t holds component v=t.
// v_t layout matches u: v_t[bh*25600 + (l*40+v)*16 + (b&15)].
// ---------------------------------------------------------------------------
__global__ __launch_bounds__(64) void k_squash0(
    const float* __restrict__ s0, float* __restrict__ v0t)
{
  const int b = blockIdx.x / 40, l = blockIdx.x % 40, t = threadIdx.x;
  float s = 0.f;
  if (t < 40) s = s0[(l*40 + t)*32 + b] * (1.f/40.f);
  float sq = s*s;
  #pragma unroll
  for (int d = 1; d < 64; d <<= 1) sq += __shfl_xor(sq, d);
  float scale = sq > 0.f ? sq / ((1.f + sq) * sqrtf(sq)) : 0.f;
  if (t < 40) v0t[(size_t)(b >> 4)*25600 + (l*40 + t)*16 + (b & 15)] = s * scale;
}

__global__ __launch_bounds__(64) void k_squash1(
    const float* __restrict__ spart, float* __restrict__ v1t)
{
  const int b = blockIdx.x / 40, l = blockIdx.x % 40, t = threadIdx.x;
  float s = 0.f;
  if (t < 40) {
    size_t off = (size_t)(b >> 4)*25600 + (l*40 + t)*16 + (b & 15);
    for (int c = 0; c < 129; ++c) s += spart[(size_t)c*51200 + off];
  }
  float sq = s*s;
  #pragma unroll
  for (int d = 1; d < 64; d <<= 1) sq += __shfl_xor(sq, d);
  float scale = sq > 0.f ? sq / ((1.f + sq) * sqrtf(sq)) : 0.f;
  if (t < 40) v1t[(size_t)(b >> 4)*25600 + (l*40 + t)*16 + (b & 15)] = s * scale;
}

__global__ __launch_bounds__(64) void k_final(
    const float* __restrict__ spart, float* __restrict__ out)
{
  const int b = blockIdx.x / 40, l = blockIdx.x % 40, t = threadIdx.x;
  float s = 0.f;
  if (t < 40) {
    size_t off = (size_t)(b >> 4)*25600 + (l*40 + t)*16 + (b & 15);
    for (int c = 0; c < 129; ++c) s += spart[(size_t)c*51200 + off];
  }
  float sq = s*s, ss = s;
  #pragma unroll
  for (int d = 1; d < 64; d <<= 1) { sq += __shfl_xor(sq, d); ss += __shfl_xor(ss, d); }
  float scale = sq > 0.f ? sq / ((1.f + sq) * sqrtf(sq)) : 0.f;
  if (t == 0) out[b*40 + l] = ss * scale;
}

// ---------------------------------------------------------------------------
// Routing pass (B: pass=1, C: pass=2). Block = (b-half, chunk of PC p's).
// Per p: stream u half-slab (25600 w) global->LDS while accumulating
// b_ij dot-partials (LDS atomics); softmax over l (per b); write/keep b1;
// then s += c*u from the staged LDS slab into registers.
// Per-block output: spart[chunk*2+bh][25600].
// ---------------------------------------------------------------------------
#define PC 10
__global__ __launch_bounds__(512) void k_route(
    const float* __restrict__ u, const float* __restrict__ vprev_t,
    float* __restrict__ b1g, float* __restrict__ spart, int pass)
{
  extern __shared__ float lds[];
  float* u_lds = lds;             // 25600 words
  float* dot_lds = lds + 25600;   // 640 = [l][b16]
  float* c_lds = dot_lds + 640;   // 640 = [l][b16]
  const int bh = blockIdx.x & 1, chunk = blockIdx.x >> 1;
  const int t = threadIdx.x;
  const int bq = t & 3, lsub = t >> 2;
  const int lv0 = lsub * 13;      // contiguous run of 13 lv's, guard lv<1600
  float sreg[13][4] = {};
  const int p0 = chunk * PC;
  const float* vp = vprev_t + (size_t)bh * 25600;
  for (int pp = 0; pp < PC; ++pp) {
    int p = p0 + pp;
    if (p >= 1287) break;
    const size_t pbase = (size_t)(bh*1287 + p);
    for (int w = t; w < 640; w += 512)
      dot_lds[w] = (pass == 1) ? 0.f : b1g[pbase*640 + w];
    __syncthreads();
    const float* up = u + pbase * 25600;
    // stream + dot accumulate
    {
      float dacc[4] = {0.f, 0.f, 0.f, 0.f};
      int cur_l = lv0 / 40;
      #pragma unroll
      for (int k = 0; k < 13; ++k) {
        int lv = lv0 + k;
        if (lv < 1600) {
          int li = lv / 40;
          if (li != cur_l) {
            if (cur_l < 40) {
              #pragma unroll
              for (int j = 0; j < 4; ++j) atomicAdd(&dot_lds[cur_l*16 + bq*4 + j], dacc[j]);
            }
            dacc[0] = dacc[1] = dacc[2] = dacc[3] = 0.f;
            cur_l = li;
          }
          int off = lv*16 + bq*4;
          float4 uu = *(const float4*)(up + off);
          float4 vv = *(const float4*)(vp + off);
          *(float4*)(u_lds + off) = uu;
          dacc[0] += uu.x*vv.x; dacc[1] += uu.y*vv.y;
          dacc[2] += uu.z*vv.z; dacc[3] += uu.w*vv.w;
        }
      }
      if (cur_l < 40) {
        #pragma unroll
        for (int j = 0; j < 4; ++j) atomicAdd(&dot_lds[cur_l*16 + bq*4 + j], dacc[j]);
      }
    }
    __syncthreads();
    // softmax over l for each of the 16 b's
    if (t < 16) {
      float m = -1e30f;
      for (int li = 0; li < 40; ++li) m = fmaxf(m, dot_lds[li*16 + t]);
      float Z = 0.f;
      for (int li = 0; li < 40; ++li) {
        float e = expf(dot_lds[li*16 + t] - m);
        c_lds[li*16 + t] = e; Z += e;
      }
      float r = 1.f / Z;
      for (int li = 0; li < 40; ++li) c_lds[li*16 + t] *= r;
    }
    if (pass == 1) {
      for (int w = t; w < 640; w += 512) b1g[pbase*640 + w] = dot_lds[w];
    }
    __syncthreads();
    // s accumulate from staged slab
    #pragma unroll
    for (int k = 0; k < 13; ++k) {
      int lv = lv0 + k;
      if (lv < 1600) {
        int li = lv / 40;
        int off = lv*16 + bq*4;
        float4 uu = *(const float4*)(u_lds + off);
        float4 cc = *(const float4*)(&c_lds[li*16 + bq*4]);
        sreg[k][0] += uu.x*cc.x; sreg[k][1] += uu.y*cc.y;
        sreg[k][2] += uu.z*cc.z; sreg[k][3] += uu.w*cc.w;
      }
    }
    __syncthreads();
  }
  float* sp = spart + ((size_t)chunk*2 + bh) * 25600;
  #pragma unroll
  for (int k = 0; k < 13; ++k) {
    int lv = lv0 + k;
    if (lv < 1600)
      *(float4*)(sp + lv*16 + bq*4) = make_float4(sreg[k][0], sreg[k][1], sreg[k][2], sreg[k][3]);
  }
}

// ---------------------------------------------------------------------------
extern "C" void kernel_launch(void* const* d_in, const int* in_sizes, int n_in,
                              void* d_out, int out_size, void* d_ws, size_t ws_size,
                              hipStream_t stream)
{
  const float* data = (const float*)d_in[0];
  const float* w1   = (const float*)d_in[1];
  const float* w2   = (const float*)d_in[2];
  const float* w3   = (const float*)d_in[3];
  const float* lw   = (const float*)d_in[4];
  const float* bg   = (const float*)d_in[5];
  const float* bb   = (const float*)d_in[6];
  const float* bm   = (const float*)d_in[7];
  const float* bv   = (const float*)d_in[8];
  const float* W    = (const float*)d_in[9];
  float* out = (float*)d_out;

  float* xt    = (float*)d_ws;              // 1,317,888 words
  float* u     = xt + 1317888;              // 65,894,400 words
  float* s0    = u + 65894400;              // 51,200
  float* v0t   = s0 + 51200;                // 51,200
  float* v1t   = v0t + 51200;               // 51,200
  float* b1g   = v1t + 51200;               // 1,647,360
  float* spart = b1g + 1647360;             // 6,604,800
  // total ~302.5 MB of workspace

  const int LDSB = (25600 + 640 + 640) * 4; // 107,520 B dynamic LDS
  hipFuncSetAttribute((const void*)k_route, hipFuncAttributeMaxDynamicSharedMemorySize, LDSB);

  hipMemsetAsync(s0, 0, 51200 * sizeof(float), stream);
  k_front<<<256, 256, 0, stream>>>(data, w1, w2, w3, lw, bg, bb, bm, bv, xt);
  k_uhat<<<810, 256, 0, stream>>>(W, xt, u, s0);
  k_squash0<<<1280, 64, 0, stream>>>(s0, v0t);
  k_route<<<258, 512, LDSB, stream>>>(u, v0t, b1g, spart, 1);
  k_squash1<<<1280, 64, 0, stream>>>(spart, v1t);
  k_route<<<258, 512, LDSB, stream>>>(u, v1t, b1g, spart, 2);
  k_final<<<1280, 64, 0, stream>>>(spart, out);
}